// Round 4
// baseline (6609.938 us; speedup 1.0000x reference)
//
#include <hip/hip_runtime.h>
#include <cstdint>

// ---------------------------------------------------------------------------
// Threefry-2x32 (JAX partitionable-mode compatible), host + device.
// ---------------------------------------------------------------------------
__host__ __device__ inline uint32_t tf_rotl32(uint32_t x, uint32_t r) {
  return (x << r) | (x >> (32u - r));
}

__host__ __device__ inline void threefry2x32(uint32_t k0, uint32_t k1,
                                             uint32_t x0, uint32_t x1,
                                             uint32_t* o0, uint32_t* o1) {
  uint32_t ks0 = k0, ks1 = k1, ks2 = k0 ^ k1 ^ 0x1BD11BDAu;
  x0 += ks0; x1 += ks1;
#define TF_R(r) { x0 += x1; x1 = tf_rotl32(x1, r); x1 ^= x0; }
  TF_R(13) TF_R(15) TF_R(26) TF_R(6)
  x0 += ks1; x1 += ks2 + 1u;
  TF_R(17) TF_R(29) TF_R(16) TF_R(24)
  x0 += ks2; x1 += ks0 + 2u;
  TF_R(13) TF_R(15) TF_R(26) TF_R(6)
  x0 += ks0; x1 += ks1 + 3u;
  TF_R(17) TF_R(29) TF_R(16) TF_R(24)
  x0 += ks1; x1 += ks2 + 4u;
  TF_R(13) TF_R(15) TF_R(26) TF_R(6)
  x0 += ks2; x1 += ks0 + 5u;
#undef TF_R
  *o0 = x0; *o1 = x1;
}

// ---------------------------------------------------------------------------
// Problem dims
// ---------------------------------------------------------------------------
#define BSZ   8192
#define KIN   784
#define HID   800
#define NOUT  10
#define NSTEP 25

// R8: golden = Eigen gebp (AVX no-FMA jaxlib): k-panels [0,264) [264,528)
// [528,784), per k-step acc = rn(acc + rn(a*b)).
// R9: a in {0,1,2} makes every product exact, so fmaf == mul+add bit-exactly.
// R10: u8-packed A in LDS + 8x4 tile -> 0.375 B/FLOP (LDS no longer binding;
//      bank conflicts 1.38e7 -> 0 confirmed in R3).
// R12 (this round): R3 regressed (225us, VALUBusy 46%, Occupancy 16.5%) —
//      latency-bound: 2-wave blocks + serial {stage -> sync -> compute}
//      exposed L2/L3 staging latency. Fix: (a) 256-thread 4-wave blocks
//      (BM=256, BN=32, same 8x4 thread tile; 800 blocks, 3200 waves);
//      (b) register prefetch double-buffer — issue tile t+1 global loads
//      before computing tile t, write to LDS after the sync. Predicted
//      gemm ~105-130us (VALU floor 82us + staging + barriers).
// ---------------------------------------------------------------------------
#define PANEL1 264
#define PANEL2 528

// ---------------------------------------------------------------------------
// Kernel 1: Poisson encoding (JAX-faithful: truncated 2^-23 grid).
// enc = temp + 1 in {0,1,2}; sp = 0.5*enc (exact power-of-2 relation).
// ---------------------------------------------------------------------------
__global__ __launch_bounds__(256) void enc_kernel(const float* __restrict__ inp,
                                                  uint8_t* __restrict__ enc,
                                                  uint32_t k0, uint32_t k1) {
  int j = blockIdx.x * blockDim.x + threadIdx.x;
  if (j >= BSZ * KIN) return;
  uint32_t o0, o1;
  threefry2x32(k0, k1, 0u, (uint32_t)j, &o0, &o1);
  uint32_t bits = o0 ^ o1;
  float r = __uint_as_float((bits >> 9) | 0x3f800000u) - 1.0f;
  float x = inp[j];
  bool cond = (2.0f * r <= fabsf(x));
  int s = (x > 0.0f) ? 1 : ((x < 0.0f) ? -1 : 0);
  enc[j] = (uint8_t)(1 + (cond ? s : 0));
}

// ---------------------------------------------------------------------------
// Kernel 2: g[b,j] = 0.5 * ((P0 + P1) + P2), Eigen panels at k=264,528.
// BM=256, BN=32, BK=16. 256 threads (4 waves), 8x4 acc per thread.
// As: packed u8 [BK][BM/4 words] (byte i of word r = A[row 4r+i][k]).
// Bs: f32 [BK][BN]. Register-prefetch double-buffer over K-tiles.
// Per kk per thread: ds_read_b64 (A, 8 rows) + ds_read_b128 (B, 4 cols),
// 8 cvt + 32 FMA. All LDS patterns <=2-way on banks (free).
// ---------------------------------------------------------------------------
#define BM 256
#define BN 32
#define BK 16
#define NTILE (KIN / BK)   // 49

__device__ __forceinline__ float cvt_ub(uint32_t x, int i) {
  return (float)((x >> (8 * i)) & 0xffu);   // folds to v_cvt_f32_ubyte_i
}

__global__ __launch_bounds__(256) void gemm_kernel(const uint8_t* __restrict__ enc,
                                                   const float* __restrict__ w1,
                                                   float* __restrict__ g) {
  __shared__ uint32_t As[BK][BM / 4];  // 4 KB
  __shared__ float Bs[BK][BN];         // 2 KB
  const int m0 = blockIdx.x * BM;
  const int n0 = blockIdx.y * BN;
  const int t  = threadIdx.x;

  // hot-loop mapping: 32 row-groups x 8 col-groups
  const int tm = t / 8;        // 0..31 -> rows tm*8 .. +7
  const int tn = t % 8;        // 0..7  -> cols tn*4 .. +3

  // A staging: 4 rows x 4 k-bytes per thread, byte-transposed via v_perm
  const int ar0 = (t % 64) * 4;   // row base 0..252
  const int ak0 = (t / 64) * 4;   // k base 0,4,8,12 (one k-slice per wave)

  // B staging: 1 row x 2 k per thread (float2)
  const int brow = t % 32;
  const int bk0  = (t / 32) * 2;  // 0,2,..,14

  const uint8_t* aptr = enc + (size_t)(m0 + ar0) * KIN + ak0;
  const float*   bptr = w1 + (size_t)(n0 + brow) * KIN + bk0;

  float acc[8][4] = {};    // current panel chain
  float tot[8][4];         // committed C (valid after first commit)

  uint32_t rA0, rA1, rA2, rA3;
  float2 rB;

  // ---- prologue: load + stage tile 0 ----
  rA0 = *(const uint32_t*)(aptr + (size_t)0 * KIN);
  rA1 = *(const uint32_t*)(aptr + (size_t)1 * KIN);
  rA2 = *(const uint32_t*)(aptr + (size_t)2 * KIN);
  rA3 = *(const uint32_t*)(aptr + (size_t)3 * KIN);
  rB  = *(const float2*)bptr;
  {
    uint32_t a01  = __builtin_amdgcn_perm(rA1, rA0, 0x05010400u);
    uint32_t a01h = __builtin_amdgcn_perm(rA1, rA0, 0x07030602u);
    uint32_t a23  = __builtin_amdgcn_perm(rA3, rA2, 0x05010400u);
    uint32_t a23h = __builtin_amdgcn_perm(rA3, rA2, 0x07030602u);
    As[ak0 + 0][ar0 >> 2] = __builtin_amdgcn_perm(a23,  a01,  0x05040100u);
    As[ak0 + 1][ar0 >> 2] = __builtin_amdgcn_perm(a23,  a01,  0x07060302u);
    As[ak0 + 2][ar0 >> 2] = __builtin_amdgcn_perm(a23h, a01h, 0x05040100u);
    As[ak0 + 3][ar0 >> 2] = __builtin_amdgcn_perm(a23h, a01h, 0x07060302u);
    Bs[bk0 + 0][brow] = rB.x;
    Bs[bk0 + 1][brow] = rB.y;
  }
  __syncthreads();

  for (int tile = 0; tile < NTILE; tile++) {
    const int k0 = tile * BK;
    const bool more = (tile + 1 < NTILE);
    // ---- issue next tile's global loads (latency hides under compute) ----
    if (more) {
      const uint8_t* ap = aptr + (size_t)(k0 + BK);
      rA0 = *(const uint32_t*)(ap + (size_t)0 * KIN);
      rA1 = *(const uint32_t*)(ap + (size_t)1 * KIN);
      rA2 = *(const uint32_t*)(ap + (size_t)2 * KIN);
      rA3 = *(const uint32_t*)(ap + (size_t)3 * KIN);
      rB  = *(const float2*)(bptr + (size_t)(k0 + BK));
    }
    // ---- compute current tile from LDS ----
#pragma unroll
    for (int kk = 0; kk < BK; kk++) {
      const int kglob = k0 + kk;
      if (kglob == PANEL1) {
#pragma unroll
        for (int mi = 0; mi < 8; mi++)
#pragma unroll
          for (int ni = 0; ni < 4; ni++) { tot[mi][ni] = acc[mi][ni]; acc[mi][ni] = 0.0f; }
      } else if (kglob == PANEL2) {
#pragma unroll
        for (int mi = 0; mi < 8; mi++)
#pragma unroll
          for (int ni = 0; ni < 4; ni++) { tot[mi][ni] = __fadd_rn(tot[mi][ni], acc[mi][ni]); acc[mi][ni] = 0.0f; }
      }
      // A fragment: 8 u8 rows (2 packed words), convert in-register
      uint2 av = *(const uint2*)&As[kk][tm * 2];
      float a[8];
      a[0] = cvt_ub(av.x, 0);
      a[1] = cvt_ub(av.x, 1);
      a[2] = cvt_ub(av.x, 2);
      a[3] = cvt_ub(av.x, 3);
      a[4] = cvt_ub(av.y, 0);
      a[5] = cvt_ub(av.y, 1);
      a[6] = cvt_ub(av.y, 2);
      a[7] = cvt_ub(av.y, 3);
      // B fragment: 4 f32
      float4 bv = *(const float4*)&Bs[kk][tn * 4];
      float b[4] = {bv.x, bv.y, bv.z, bv.w};
#pragma unroll
      for (int mi = 0; mi < 8; mi++)
#pragma unroll
        for (int ni = 0; ni < 4; ni++)
          acc[mi][ni] = __builtin_fmaf(a[mi], b[ni], acc[mi][ni]);  // exact product => == mul+add
    }
    __syncthreads();   // all waves done reading this tile
    // ---- stage next tile into LDS (compiler waits vmcnt before ds_write) ----
    if (more) {
      uint32_t a01  = __builtin_amdgcn_perm(rA1, rA0, 0x05010400u);
      uint32_t a01h = __builtin_amdgcn_perm(rA1, rA0, 0x07030602u);
      uint32_t a23  = __builtin_amdgcn_perm(rA3, rA2, 0x05010400u);
      uint32_t a23h = __builtin_amdgcn_perm(rA3, rA2, 0x07030602u);
      As[ak0 + 0][ar0 >> 2] = __builtin_amdgcn_perm(a23,  a01,  0x05040100u);
      As[ak0 + 1][ar0 >> 2] = __builtin_amdgcn_perm(a23,  a01,  0x07060302u);
      As[ak0 + 2][ar0 >> 2] = __builtin_amdgcn_perm(a23h, a01h, 0x05040100u);
      As[ak0 + 3][ar0 >> 2] = __builtin_amdgcn_perm(a23h, a01h, 0x07060302u);
      Bs[bk0 + 0][brow] = rB.x;
      Bs[bk0 + 1][brow] = rB.y;
      __syncthreads();
    }
  }

#pragma unroll
  for (int mi = 0; mi < 8; mi++) {
    float* dst = g + (size_t)(m0 + tm * 8 + mi) * HID + n0 + tn * 4;
    float4 o;
    o.x = __fmul_rn(0.5f, __fadd_rn(tot[mi][0], acc[mi][0]));  // (P0+P1)+P2, exact 0.5
    o.y = __fmul_rn(0.5f, __fadd_rn(tot[mi][1], acc[mi][1]));
    o.z = __fmul_rn(0.5f, __fadd_rn(tot[mi][2], acc[mi][2]));
    o.w = __fmul_rn(0.5f, __fadd_rn(tot[mi][3], acc[mi][3]));
    *(float4*)dst = o;
  }
}

// ---------------------------------------------------------------------------
// Kernel 3: f32 membrane update + spike + mem2 accumulation.
// m = rn(rn(0.95f*mem) + rn(0.05f*g)) — mul/mul/add; products NOT exact here,
// so FMA contraction would change bits — keep split __fmul_rn/__fadd_rn.
// ---------------------------------------------------------------------------
__global__ __launch_bounds__(256) void update_kernel(const float* __restrict__ g,
                                                     float* __restrict__ mem1,
                                                     const float* __restrict__ w2,
                                                     float* __restrict__ mem2) {
  __shared__ float w2s[NOUT * HID];   // 32 KB
  for (int i = threadIdx.x; i < NOUT * HID; i += 256) w2s[i] = w2[i];
  __syncthreads();

  const int wave = threadIdx.x / 64;
  const int lane = threadIdx.x % 64;
  const int b = blockIdx.x * 4 + wave;

  const float* grow = g + (size_t)b * HID;
  float* mrow = mem1 + (size_t)b * HID;

  float acc[NOUT];
#pragma unroll
  for (int i = 0; i < NOUT; i++) acc[i] = 0.0f;

  for (int j = lane; j < HID; j += 64) {
    float m = __fadd_rn(__fmul_rn(0.95f, mrow[j]), __fmul_rn(0.05f, grow[j]));
    bool spike = __fadd_rn(m, -1.0f) > 0.0f;
    mrow[j] = spike ? __fadd_rn(m, -1.0f) : m;
    if (spike) {
#pragma unroll
      for (int i = 0; i < NOUT; i++) acc[i] += w2s[i * HID + j];
    }
  }
  // mem2 never feeds back into spike decisions: reduction-order noise ~1e-7
  // << 3.6e-3 threshold, no need to replicate ref's order here.
#pragma unroll
  for (int i = 0; i < NOUT; i++) {
    float v = acc[i];
    for (int off = 32; off > 0; off >>= 1) v += __shfl_down(v, off);
    if (lane == 0) mem2[(size_t)b * NOUT + i] += v;
  }
}

// ---------------------------------------------------------------------------
// Kernel 4: out = mem2 / num_steps
// ---------------------------------------------------------------------------
__global__ __launch_bounds__(256) void finalize_kernel(const float* __restrict__ mem2,
                                                       const int* __restrict__ ns,
                                                       float* __restrict__ out) {
  int i = blockIdx.x * blockDim.x + threadIdx.x;
  if (i < BSZ * NOUT) out[i] = mem2[i] / (float)(*ns);
}

// ---------------------------------------------------------------------------
extern "C" void kernel_launch(void* const* d_in, const int* in_sizes, int n_in,
                              void* d_out, int out_size, void* d_ws, size_t ws_size,
                              hipStream_t stream) {
  const float* inp = (const float*)d_in[0];
  const float* w1  = (const float*)d_in[1];
  const float* w2  = (const float*)d_in[2];
  const int*   dns = (const int*)d_in[3];
  float* out = (float*)d_out;

  char* ws = (char*)d_ws;
  size_t off = 0;
  uint8_t* enc = (uint8_t*)(ws + off);  off += (size_t)BSZ * KIN;          // 6.4 MB
  off = (off + 255) & ~(size_t)255;
  float* g    = (float*)(ws + off);     off += (size_t)BSZ * HID * 4;      // 26.2 MB
  float* mem1 = (float*)(ws + off);     off += (size_t)BSZ * HID * 4;      // 26.2 MB
  float* mem2 = (float*)(ws + off);     off += (size_t)BSZ * NOUT * 4;     // 0.33 MB

  (void)hipMemsetAsync(mem1, 0, (size_t)BSZ * HID * 4, stream);
  (void)hipMemsetAsync(mem2, 0, (size_t)BSZ * NOUT * 4, stream);

  // Step keys: partitionable split — key_t = threefry((0,42), (0,t)).
  uint32_t keys[NSTEP][2];
  for (int t = 0; t < NSTEP; t++)
    threefry2x32(0u, 42u, 0u, (uint32_t)t, &keys[t][0], &keys[t][1]);

  const int n_elem = BSZ * KIN;
  for (int t = 0; t < NSTEP; t++) {
    enc_kernel<<<(n_elem + 255) / 256, 256, 0, stream>>>(inp, enc, keys[t][0], keys[t][1]);
    gemm_kernel<<<dim3(BSZ / BM, HID / BN), 256, 0, stream>>>(enc, w1, g);
    update_kernel<<<BSZ / 4, 256, 0, stream>>>(g, mem1, w2, mem2);
  }
  finalize_kernel<<<(BSZ * NOUT + 255) / 256, 256, 0, stream>>>(mem2, dns, out);
}

// Round 5
// 4799.567 us; speedup vs baseline: 1.3772x; 1.3772x over previous
//
#include <hip/hip_runtime.h>
#include <cstdint>

// ---------------------------------------------------------------------------
// Threefry-2x32 (JAX partitionable-mode compatible), host + device.
// ---------------------------------------------------------------------------
__host__ __device__ inline uint32_t tf_rotl32(uint32_t x, uint32_t r) {
  return (x << r) | (x >> (32u - r));
}

__host__ __device__ inline void threefry2x32(uint32_t k0, uint32_t k1,
                                             uint32_t x0, uint32_t x1,
                                             uint32_t* o0, uint32_t* o1) {
  uint32_t ks0 = k0, ks1 = k1, ks2 = k0 ^ k1 ^ 0x1BD11BDAu;
  x0 += ks0; x1 += ks1;
#define TF_R(r) { x0 += x1; x1 = tf_rotl32(x1, r); x1 ^= x0; }
  TF_R(13) TF_R(15) TF_R(26) TF_R(6)
  x0 += ks1; x1 += ks2 + 1u;
  TF_R(17) TF_R(29) TF_R(16) TF_R(24)
  x0 += ks2; x1 += ks0 + 2u;
  TF_R(13) TF_R(15) TF_R(26) TF_R(6)
  x0 += ks0; x1 += ks1 + 3u;
  TF_R(17) TF_R(29) TF_R(16) TF_R(24)
  x0 += ks1; x1 += ks2 + 4u;
  TF_R(13) TF_R(15) TF_R(26) TF_R(6)
  x0 += ks2; x1 += ks0 + 5u;
#undef TF_R
  *o0 = x0; *o1 = x1;
}

// ---------------------------------------------------------------------------
// Problem dims
// ---------------------------------------------------------------------------
#define BSZ   8192
#define KIN   784
#define HID   800
#define NOUT  10
#define NSTEP 25

// R8: golden = Eigen gebp (AVX no-FMA jaxlib): k-panels [0,264) [264,528)
// [528,784), per k-step acc = rn(acc + rn(a*b)).
// R9: a in {0,1,2} makes every product exact, so fmaf == mul+add bit-exactly.
// R13 (this round): R3/R4 regressed because halving wave count (3200) killed
//   latency hiding (occ 38%->16%, VALUBusy 52->44). Revert to the proven
//   6400-wave 4x4-tile shape; keep u8 A (frag read = 1 broadcast ds_read_b32);
//   fix the 8-way B-staging bank conflict (brow = t%32 now); LDS double-buffer
//   with split staging roles (waves 0-1 stage A, 2-3 stage B) -> 1 barrier
//   per tile, global prefetch hidden under the 16-kk FMA phase.
// ---------------------------------------------------------------------------
#define PANEL1 264
#define PANEL2 528

// ---------------------------------------------------------------------------
// Kernel 1: Poisson encoding (JAX-faithful: truncated 2^-23 grid).
// enc = temp + 1 in {0,1,2}; sp = 0.5*enc (exact power-of-2 relation).
// ---------------------------------------------------------------------------
__global__ __launch_bounds__(256) void enc_kernel(const float* __restrict__ inp,
                                                  uint8_t* __restrict__ enc,
                                                  uint32_t k0, uint32_t k1) {
  int j = blockIdx.x * blockDim.x + threadIdx.x;
  if (j >= BSZ * KIN) return;
  uint32_t o0, o1;
  threefry2x32(k0, k1, 0u, (uint32_t)j, &o0, &o1);
  uint32_t bits = o0 ^ o1;
  float r = __uint_as_float((bits >> 9) | 0x3f800000u) - 1.0f;
  float x = inp[j];
  bool cond = (2.0f * r <= fabsf(x));
  int s = (x > 0.0f) ? 1 : ((x < 0.0f) ? -1 : 0);
  enc[j] = (uint8_t)(1 + (cond ? s : 0));
}

// ---------------------------------------------------------------------------
// Kernel 2: g[b,j] = 0.5 * ((P0 + P1) + P2), Eigen panels at k=264,528.
// BM=128, BN=32, BK=16. 256 threads (4 waves), 4x4 acc per thread.
// As: packed u8 [2][BK][BM/4 words] (byte i of word r = A[row 4r+i][k]).
// Bs: f32 [2][BK][BN]. Double-buffered; waves 0-1 stage A, waves 2-3 stage B.
// Per kk: ds_read_b32 (A, 8-addr broadcast) + ds_read_b128 (B, 8-addr
// broadcast) + 4 cvt + 16 FMA. All LDS patterns <=2-way on banks (free).
// ---------------------------------------------------------------------------
#define BM 128
#define BN 32
#define BK 16
#define NTILE (KIN / BK)   // 49

__device__ __forceinline__ float cvt_ub(uint32_t x, int i) {
  return (float)((x >> (8 * i)) & 0xffu);   // folds to v_cvt_f32_ubyte_i
}

__global__ __launch_bounds__(256) void gemm_kernel(const uint8_t* __restrict__ enc,
                                                   const float* __restrict__ w1,
                                                   float* __restrict__ g) {
  __shared__ uint32_t As[2][BK][BM / 4];  // 2 x 2 KB
  __shared__ float    Bs[2][BK][BN];      // 2 x 2 KB
  const int m0 = blockIdx.x * BM;
  const int n0 = blockIdx.y * BN;
  const int t  = threadIdx.x;

  // compute mapping: 32 row-groups x 8 col-groups, 4x4 per thread
  const int tm = t / 8;        // 0..31 -> rows tm*4 .. +3
  const int tn = t % 8;        // 0..7  -> cols tn*4 .. +3

  // staging roles: threads 0..127 stage A (4 rows x 4 k bytes each),
  //                threads 128..255 stage B (1 row x 4 k f32 each).
  const bool isA = (t < 128);
  const int u    = t & 127;
  const int ar0  = (u & 31) * 4;       // A: row base 0..124
  const int ak0  = (u >> 5) * 4;       // A: k base 0,4,8,12
  const int brow = u & 31;             // B: row 0..31
  const int bk0  = (u >> 5) * 4;       // B: k base 0,4,8,12

  const uint8_t* aptr = enc + (size_t)(m0 + ar0) * KIN + ak0;
  const float*   bptr = w1 + (size_t)(n0 + brow) * KIN + bk0;

  uint32_t rA0, rA1, rA2, rA3;
  float4 rB;

  float acc[4][4] = {};    // current panel chain
  float tot[4][4];         // committed C (valid after first commit)

#define LOAD_TILE(K0G)                                               \
  if (isA) {                                                         \
    const uint8_t* ap = aptr + (K0G);                                \
    rA0 = *(const uint32_t*)(ap + (size_t)0 * KIN);                  \
    rA1 = *(const uint32_t*)(ap + (size_t)1 * KIN);                  \
    rA2 = *(const uint32_t*)(ap + (size_t)2 * KIN);                  \
    rA3 = *(const uint32_t*)(ap + (size_t)3 * KIN);                  \
  } else {                                                           \
    rB = *(const float4*)(bptr + (K0G));                             \
  }

#define STORE_TILE(P)                                                \
  if (isA) {                                                         \
    uint32_t a01  = __builtin_amdgcn_perm(rA1, rA0, 0x05010400u);    \
    uint32_t a01h = __builtin_amdgcn_perm(rA1, rA0, 0x07030602u);    \
    uint32_t a23  = __builtin_amdgcn_perm(rA3, rA2, 0x05010400u);    \
    uint32_t a23h = __builtin_amdgcn_perm(rA3, rA2, 0x07030602u);    \
    As[P][ak0 + 0][ar0 >> 2] = __builtin_amdgcn_perm(a23,  a01,  0x05040100u); \
    As[P][ak0 + 1][ar0 >> 2] = __builtin_amdgcn_perm(a23,  a01,  0x07060302u); \
    As[P][ak0 + 2][ar0 >> 2] = __builtin_amdgcn_perm(a23h, a01h, 0x05040100u); \
    As[P][ak0 + 3][ar0 >> 2] = __builtin_amdgcn_perm(a23h, a01h, 0x07060302u); \
  } else {                                                           \
    Bs[P][bk0 + 0][brow] = rB.x;                                     \
    Bs[P][bk0 + 1][brow] = rB.y;                                     \
    Bs[P][bk0 + 2][brow] = rB.z;                                     \
    Bs[P][bk0 + 3][brow] = rB.w;                                     \
  }

  // ---- prologue: stage tile 0 into buffer 0 ----
  LOAD_TILE(0)
  STORE_TILE(0)
  __syncthreads();

  int p = 0;
  for (int tile = 0; tile < NTILE; tile++) {
    const int kbase = tile * BK;
    const bool more = (tile + 1 < NTILE);
    // issue next tile's global loads; latency hides under compute
    if (more) { LOAD_TILE(kbase + BK) }
    // compute current tile from LDS buffer p
#pragma unroll
    for (int kk = 0; kk < BK; kk++) {
      const int kglob = kbase + kk;
      if (kglob == PANEL1) {
#pragma unroll
        for (int mi = 0; mi < 4; mi++)
#pragma unroll
          for (int ni = 0; ni < 4; ni++) { tot[mi][ni] = acc[mi][ni]; acc[mi][ni] = 0.0f; }
      } else if (kglob == PANEL2) {
#pragma unroll
        for (int mi = 0; mi < 4; mi++)
#pragma unroll
          for (int ni = 0; ni < 4; ni++) { tot[mi][ni] = __fadd_rn(tot[mi][ni], acc[mi][ni]); acc[mi][ni] = 0.0f; }
      }
      // A fragment: 4 u8 rows in one packed word (8-addr broadcast read)
      uint32_t aw = As[p][kk][tm];
      float a[4];
      a[0] = cvt_ub(aw, 0);
      a[1] = cvt_ub(aw, 1);
      a[2] = cvt_ub(aw, 2);
      a[3] = cvt_ub(aw, 3);
      // B fragment: 4 f32 (8-addr broadcast read)
      float4 bv = *(const float4*)&Bs[p][kk][tn * 4];
      float b[4] = {bv.x, bv.y, bv.z, bv.w};
#pragma unroll
      for (int mi = 0; mi < 4; mi++)
#pragma unroll
        for (int ni = 0; ni < 4; ni++)
          acc[mi][ni] = __builtin_fmaf(a[mi], b[ni], acc[mi][ni]);  // exact product => == mul+add
    }
    // stage next tile into the other buffer (no reader until after sync)
    if (more) { STORE_TILE(p ^ 1) }
    __syncthreads();
    p ^= 1;
  }
#undef LOAD_TILE
#undef STORE_TILE

#pragma unroll
  for (int mi = 0; mi < 4; mi++) {
    float* dst = g + (size_t)(m0 + tm * 4 + mi) * HID + n0 + tn * 4;
    float4 o;
    o.x = __fmul_rn(0.5f, __fadd_rn(tot[mi][0], acc[mi][0]));  // (P0+P1)+P2, exact 0.5
    o.y = __fmul_rn(0.5f, __fadd_rn(tot[mi][1], acc[mi][1]));
    o.z = __fmul_rn(0.5f, __fadd_rn(tot[mi][2], acc[mi][2]));
    o.w = __fmul_rn(0.5f, __fadd_rn(tot[mi][3], acc[mi][3]));
    *(float4*)dst = o;
  }
}

// ---------------------------------------------------------------------------
// Kernel 3: f32 membrane update + spike + mem2 accumulation.
// m = rn(rn(0.95f*mem) + rn(0.05f*g)) — mul/mul/add; products NOT exact here,
// so FMA contraction would change bits — keep split __fmul_rn/__fadd_rn.
// ---------------------------------------------------------------------------
__global__ __launch_bounds__(256) void update_kernel(const float* __restrict__ g,
                                                     float* __restrict__ mem1,
                                                     const float* __restrict__ w2,
                                                     float* __restrict__ mem2) {
  __shared__ float w2s[NOUT * HID];   // 32 KB
  for (int i = threadIdx.x; i < NOUT * HID; i += 256) w2s[i] = w2[i];
  __syncthreads();

  const int wave = threadIdx.x / 64;
  const int lane = threadIdx.x % 64;
  const int b = blockIdx.x * 4 + wave;

  const float* grow = g + (size_t)b * HID;
  float* mrow = mem1 + (size_t)b * HID;

  float acc[NOUT];
#pragma unroll
  for (int i = 0; i < NOUT; i++) acc[i] = 0.0f;

  for (int j = lane; j < HID; j += 64) {
    float m = __fadd_rn(__fmul_rn(0.95f, mrow[j]), __fmul_rn(0.05f, grow[j]));
    bool spike = __fadd_rn(m, -1.0f) > 0.0f;
    mrow[j] = spike ? __fadd_rn(m, -1.0f) : m;
    if (spike) {
#pragma unroll
      for (int i = 0; i < NOUT; i++) acc[i] += w2s[i * HID + j];
    }
  }
  // mem2 never feeds back into spike decisions: reduction-order noise ~1e-7
  // << 3.6e-3 threshold, no need to replicate ref's order here.
#pragma unroll
  for (int i = 0; i < NOUT; i++) {
    float v = acc[i];
    for (int off = 32; off > 0; off >>= 1) v += __shfl_down(v, off);
    if (lane == 0) mem2[(size_t)b * NOUT + i] += v;
  }
}

// ---------------------------------------------------------------------------
// Kernel 4: out = mem2 / num_steps
// ---------------------------------------------------------------------------
__global__ __launch_bounds__(256) void finalize_kernel(const float* __restrict__ mem2,
                                                       const int* __restrict__ ns,
                                                       float* __restrict__ out) {
  int i = blockIdx.x * blockDim.x + threadIdx.x;
  if (i < BSZ * NOUT) out[i] = mem2[i] / (float)(*ns);
}

// ---------------------------------------------------------------------------
extern "C" void kernel_launch(void* const* d_in, const int* in_sizes, int n_in,
                              void* d_out, int out_size, void* d_ws, size_t ws_size,
                              hipStream_t stream) {
  const float* inp = (const float*)d_in[0];
  const float* w1  = (const float*)d_in[1];
  const float* w2  = (const float*)d_in[2];
  const int*   dns = (const int*)d_in[3];
  float* out = (float*)d_out;

  char* ws = (char*)d_ws;
  size_t off = 0;
  uint8_t* enc = (uint8_t*)(ws + off);  off += (size_t)BSZ * KIN;          // 6.4 MB
  off = (off + 255) & ~(size_t)255;
  float* g    = (float*)(ws + off);     off += (size_t)BSZ * HID * 4;      // 26.2 MB
  float* mem1 = (float*)(ws + off);     off += (size_t)BSZ * HID * 4;      // 26.2 MB
  float* mem2 = (float*)(ws + off);     off += (size_t)BSZ * NOUT * 4;     // 0.33 MB

  (void)hipMemsetAsync(mem1, 0, (size_t)BSZ * HID * 4, stream);
  (void)hipMemsetAsync(mem2, 0, (size_t)BSZ * NOUT * 4, stream);

  // Step keys: partitionable split — key_t = threefry((0,42), (0,t)).
  uint32_t keys[NSTEP][2];
  for (int t = 0; t < NSTEP; t++)
    threefry2x32(0u, 42u, 0u, (uint32_t)t, &keys[t][0], &keys[t][1]);

  const int n_elem = BSZ * KIN;
  for (int t = 0; t < NSTEP; t++) {
    enc_kernel<<<(n_elem + 255) / 256, 256, 0, stream>>>(inp, enc, keys[t][0], keys[t][1]);
    gemm_kernel<<<dim3(BSZ / BM, HID / BN), 256, 0, stream>>>(enc, w1, g);
    update_kernel<<<BSZ / 4, 256, 0, stream>>>(g, mem1, w2, mem2);
  }
  finalize_kernel<<<(BSZ * NOUT + 255) / 256, 256, 0, stream>>>(mem2, dns, out);
}

// Round 7
// 4754.451 us; speedup vs baseline: 1.3903x; 1.0095x over previous
//
#include <hip/hip_runtime.h>
#include <cstdint>

// ---------------------------------------------------------------------------
// Threefry-2x32 (JAX partitionable-mode compatible), host + device.
// ---------------------------------------------------------------------------
__host__ __device__ inline uint32_t tf_rotl32(uint32_t x, uint32_t r) {
  return (x << r) | (x >> (32u - r));
}

__host__ __device__ inline void threefry2x32(uint32_t k0, uint32_t k1,
                                             uint32_t x0, uint32_t x1,
                                             uint32_t* o0, uint32_t* o1) {
  uint32_t ks0 = k0, ks1 = k1, ks2 = k0 ^ k1 ^ 0x1BD11BDAu;
  x0 += ks0; x1 += ks1;
#define TF_R(r) { x0 += x1; x1 = tf_rotl32(x1, r); x1 ^= x0; }
  TF_R(13) TF_R(15) TF_R(26) TF_R(6)
  x0 += ks1; x1 += ks2 + 1u;
  TF_R(17) TF_R(29) TF_R(16) TF_R(24)
  x0 += ks2; x1 += ks0 + 2u;
  TF_R(13) TF_R(15) TF_R(26) TF_R(6)
  x0 += ks0; x1 += ks1 + 3u;
  TF_R(17) TF_R(29) TF_R(16) TF_R(24)
  x0 += ks1; x1 += ks2 + 4u;
  TF_R(13) TF_R(15) TF_R(26) TF_R(6)
  x0 += ks2; x1 += ks0 + 5u;
#undef TF_R
  *o0 = x0; *o1 = x1;
}

// ---------------------------------------------------------------------------
// Problem dims
// ---------------------------------------------------------------------------
#define BSZ   8192
#define KIN   784
#define HID   800
#define NOUT  10
#define NSTEP 25

// R8: golden = Eigen gebp (AVX no-FMA jaxlib): k-panels [0,264) [264,528)
// [528,784), per k-step acc = rn(acc + rn(a*b)).
// R9: a in {0,1,2} makes every product exact, so fmaf == mul+add bit-exactly.
// R13: u8-packed A + fixed B staging + dbuf: 175us, conflicts->0,
//   VALUBusy 67% -> VALU-issue bound + fixed stalls (40 SIMD-cyc/kk MAC).
// R14/R15 (this round): v_pk_fma_f32. R6 compile fail: VOP3P needs ALL srcs
//   as 64-bit pairs (op_sel can't widen a scalar reg). Fix: a-values as two
//   natural pairs am[0]={a0,a1}, am[1]={a2,a3}; broadcast one half to both
//   result lanes via op_sel:[h,0,0] op_sel_hi:[h,1,1]. Inner kk = 8 pk_fma
//   + 4 cvt = 24 SIMD-cyc (was 40). Each half is IEEE v_fma_f32 rounding;
//   pairing over independent outputs => chain bit-exact.
// ---------------------------------------------------------------------------
#define PANEL1 264
#define PANEL2 528

// ---------------------------------------------------------------------------
// Kernel 1: Poisson encoding (JAX-faithful: truncated 2^-23 grid).
// enc = temp + 1 in {0,1,2}; sp = 0.5*enc (exact power-of-2 relation).
// ---------------------------------------------------------------------------
__global__ __launch_bounds__(256) void enc_kernel(const float* __restrict__ inp,
                                                  uint8_t* __restrict__ enc,
                                                  uint32_t k0, uint32_t k1) {
  int j = blockIdx.x * blockDim.x + threadIdx.x;
  if (j >= BSZ * KIN) return;
  uint32_t o0, o1;
  threefry2x32(k0, k1, 0u, (uint32_t)j, &o0, &o1);
  uint32_t bits = o0 ^ o1;
  float r = __uint_as_float((bits >> 9) | 0x3f800000u) - 1.0f;
  float x = inp[j];
  bool cond = (2.0f * r <= fabsf(x));
  int s = (x > 0.0f) ? 1 : ((x < 0.0f) ? -1 : 0);
  enc[j] = (uint8_t)(1 + (cond ? s : 0));
}

// ---------------------------------------------------------------------------
// Kernel 2: g[b,j] = 0.5 * ((P0 + P1) + P2), Eigen panels at k=264,528.
// BM=128, BN=32, BK=16. 256 threads (4 waves), 4x4 acc per thread.
// As: packed u8 [2][BK][BM/4 words]; Bs: f32 [2][BK][BN]. Double-buffered;
// waves 0-1 stage A, waves 2-3 stage B. Inner: 8 v_pk_fma_f32 + 4 cvt.
// ---------------------------------------------------------------------------
#define BM 128
#define BN 32
#define BK 16
#define NTILE (KIN / BK)   // 49

typedef float f32x2 __attribute__((ext_vector_type(2)));

__device__ __forceinline__ float cvt_ub(uint32_t x, int i) {
  return (float)((x >> (8 * i)) & 0xffu);   // folds to v_cvt_f32_ubyte_i
}

// acc.lo = fma(a.lo, b.lo, acc.lo); acc.hi = fma(a.lo, b.hi, acc.hi)
// op_sel:[0,..]=lo-of-src0 for lo result; op_sel_hi:[0,..]=lo-of-src0 for hi
// result => src0.lo broadcast. Per-half rounding == v_fma_f32 (bit-exact).
__device__ __forceinline__ void pk_fma_lo(f32x2& acc, f32x2 a, f32x2 b) {
  asm("v_pk_fma_f32 %0, %1, %2, %0 op_sel:[0,0,0] op_sel_hi:[0,1,1]"
      : "+v"(acc)
      : "v"(a), "v"(b));
}
// same but broadcasting src0.hi
__device__ __forceinline__ void pk_fma_hi(f32x2& acc, f32x2 a, f32x2 b) {
  asm("v_pk_fma_f32 %0, %1, %2, %0 op_sel:[1,0,0] op_sel_hi:[1,1,1]"
      : "+v"(acc)
      : "v"(a), "v"(b));
}

__global__ __launch_bounds__(256) void gemm_kernel(const uint8_t* __restrict__ enc,
                                                   const float* __restrict__ w1,
                                                   float* __restrict__ g) {
  __shared__ uint32_t As[2][BK][BM / 4];  // 2 x 2 KB
  __shared__ float    Bs[2][BK][BN];      // 2 x 2 KB
  const int m0 = blockIdx.x * BM;
  const int n0 = blockIdx.y * BN;
  const int t  = threadIdx.x;

  // compute mapping: 32 row-groups x 8 col-groups, 4x4 per thread
  const int tm = t / 8;        // 0..31 -> rows tm*4 .. +3
  const int tn = t % 8;        // 0..7  -> cols tn*4 .. +3

  // staging roles: threads 0..127 stage A (4 rows x 4 k bytes each),
  //                threads 128..255 stage B (1 row x 4 k f32 each).
  const bool isA = (t < 128);
  const int u    = t & 127;
  const int ar0  = (u & 31) * 4;       // A: row base 0..124
  const int ak0  = (u >> 5) * 4;       // A: k base 0,4,8,12
  const int brow = u & 31;             // B: row 0..31
  const int bk0  = (u >> 5) * 4;       // B: k base 0,4,8,12

  const uint8_t* aptr = enc + (size_t)(m0 + ar0) * KIN + ak0;
  const float*   bptr = w1 + (size_t)(n0 + brow) * KIN + bk0;

  uint32_t rA0, rA1, rA2, rA3;
  float4 rB;

  f32x2 acc[4][2];   // current panel chain: [mi][nj] covers cols 2nj,2nj+1
  f32x2 tot[4][2];   // committed C (valid after first commit)
#pragma unroll
  for (int mi = 0; mi < 4; mi++)
#pragma unroll
    for (int nj = 0; nj < 2; nj++) acc[mi][nj] = (f32x2)(0.0f);

#define LOAD_TILE(K0G)                                               \
  if (isA) {                                                         \
    const uint8_t* ap = aptr + (K0G);                                \
    rA0 = *(const uint32_t*)(ap + (size_t)0 * KIN);                  \
    rA1 = *(const uint32_t*)(ap + (size_t)1 * KIN);                  \
    rA2 = *(const uint32_t*)(ap + (size_t)2 * KIN);                  \
    rA3 = *(const uint32_t*)(ap + (size_t)3 * KIN);                  \
  } else {                                                           \
    rB = *(const float4*)(bptr + (K0G));                             \
  }

#define STORE_TILE(P)                                                \
  if (isA) {                                                         \
    uint32_t a01  = __builtin_amdgcn_perm(rA1, rA0, 0x05010400u);    \
    uint32_t a01h = __builtin_amdgcn_perm(rA1, rA0, 0x07030602u);    \
    uint32_t a23  = __builtin_amdgcn_perm(rA3, rA2, 0x05010400u);    \
    uint32_t a23h = __builtin_amdgcn_perm(rA3, rA2, 0x07030602u);    \
    As[P][ak0 + 0][ar0 >> 2] = __builtin_amdgcn_perm(a23,  a01,  0x05040100u); \
    As[P][ak0 + 1][ar0 >> 2] = __builtin_amdgcn_perm(a23,  a01,  0x07060302u); \
    As[P][ak0 + 2][ar0 >> 2] = __builtin_amdgcn_perm(a23h, a01h, 0x05040100u); \
    As[P][ak0 + 3][ar0 >> 2] = __builtin_amdgcn_perm(a23h, a01h, 0x07060302u); \
  } else {                                                           \
    Bs[P][bk0 + 0][brow] = rB.x;                                     \
    Bs[P][bk0 + 1][brow] = rB.y;                                     \
    Bs[P][bk0 + 2][brow] = rB.z;                                     \
    Bs[P][bk0 + 3][brow] = rB.w;                                     \
  }

  // ---- prologue: stage tile 0 into buffer 0 ----
  LOAD_TILE(0)
  STORE_TILE(0)
  __syncthreads();

  int p = 0;
  for (int tile = 0; tile < NTILE; tile++) {
    const int kbase = tile * BK;
    const bool more = (tile + 1 < NTILE);
    // issue next tile's global loads; latency hides under compute
    if (more) { LOAD_TILE(kbase + BK) }
    // compute current tile from LDS buffer p
#pragma unroll
    for (int kk = 0; kk < BK; kk++) {
      const int kglob = kbase + kk;
      if (kglob == PANEL1) {
#pragma unroll
        for (int mi = 0; mi < 4; mi++)
#pragma unroll
          for (int nj = 0; nj < 2; nj++) {
            tot[mi][nj] = acc[mi][nj];
            acc[mi][nj] = (f32x2)(0.0f);
          }
      } else if (kglob == PANEL2) {
#pragma unroll
        for (int mi = 0; mi < 4; mi++)
#pragma unroll
          for (int nj = 0; nj < 2; nj++) {
            tot[mi][nj].x = __fadd_rn(tot[mi][nj].x, acc[mi][nj].x);
            tot[mi][nj].y = __fadd_rn(tot[mi][nj].y, acc[mi][nj].y);
            acc[mi][nj] = (f32x2)(0.0f);
          }
      }
      // A fragment: 4 u8 rows in one packed word (8-addr broadcast read);
      // converts land in two natural f32 pairs
      uint32_t aw = As[p][kk][tm];
      f32x2 am[2];
      am[0].x = cvt_ub(aw, 0);
      am[0].y = cvt_ub(aw, 1);
      am[1].x = cvt_ub(aw, 2);
      am[1].y = cvt_ub(aw, 3);
      // B fragment: 4 f32 (8-addr broadcast read) = two natural pairs
      float4 bv = *(const float4*)&Bs[p][kk][tn * 4];
      f32x2 b2[2];
      b2[0].x = bv.x; b2[0].y = bv.y;
      b2[1].x = bv.z; b2[1].y = bv.w;
      // rows: mi = 2*mp + h  (h = which half of am[mp] broadcasts)
#pragma unroll
      for (int mp = 0; mp < 2; mp++) {
        pk_fma_lo(acc[2 * mp + 0][0], am[mp], b2[0]);
        pk_fma_lo(acc[2 * mp + 0][1], am[mp], b2[1]);
        pk_fma_hi(acc[2 * mp + 1][0], am[mp], b2[0]);
        pk_fma_hi(acc[2 * mp + 1][1], am[mp], b2[1]);
      }
    }
    // stage next tile into the other buffer (no reader until after sync)
    if (more) { STORE_TILE(p ^ 1) }
    __syncthreads();
    p ^= 1;
  }
#undef LOAD_TILE
#undef STORE_TILE

#pragma unroll
  for (int mi = 0; mi < 4; mi++) {
    float* dst = g + (size_t)(m0 + tm * 4 + mi) * HID + n0 + tn * 4;
    float4 o;
    o.x = __fmul_rn(0.5f, __fadd_rn(tot[mi][0].x, acc[mi][0].x));  // (P0+P1)+P2, exact 0.5
    o.y = __fmul_rn(0.5f, __fadd_rn(tot[mi][0].y, acc[mi][0].y));
    o.z = __fmul_rn(0.5f, __fadd_rn(tot[mi][1].x, acc[mi][1].x));
    o.w = __fmul_rn(0.5f, __fadd_rn(tot[mi][1].y, acc[mi][1].y));
    *(float4*)dst = o;
  }
}

// ---------------------------------------------------------------------------
// Kernel 3: f32 membrane update + spike + mem2 accumulation.
// m = rn(rn(0.95f*mem) + rn(0.05f*g)) — mul/mul/add; products NOT exact here,
// so FMA contraction would change bits — keep split __fmul_rn/__fadd_rn.
// ---------------------------------------------------------------------------
__global__ __launch_bounds__(256) void update_kernel(const float* __restrict__ g,
                                                     float* __restrict__ mem1,
                                                     const float* __restrict__ w2,
                                                     float* __restrict__ mem2) {
  __shared__ float w2s[NOUT * HID];   // 32 KB
  for (int i = threadIdx.x; i < NOUT * HID; i += 256) w2s[i] = w2[i];
  __syncthreads();

  const int wave = threadIdx.x / 64;
  const int lane = threadIdx.x % 64;
  const int b = blockIdx.x * 4 + wave;

  const float* grow = g + (size_t)b * HID;
  float* mrow = mem1 + (size_t)b * HID;

  float acc[NOUT];
#pragma unroll
  for (int i = 0; i < NOUT; i++) acc[i] = 0.0f;

  for (int j = lane; j < HID; j += 64) {
    float m = __fadd_rn(__fmul_rn(0.95f, mrow[j]), __fmul_rn(0.05f, grow[j]));
    bool spike = __fadd_rn(m, -1.0f) > 0.0f;
    mrow[j] = spike ? __fadd_rn(m, -1.0f) : m;
    if (spike) {
#pragma unroll
      for (int i = 0; i < NOUT; i++) acc[i] += w2s[i * HID + j];
    }
  }
  // mem2 never feeds back into spike decisions: reduction-order noise ~1e-7
  // << 3.6e-3 threshold, no need to replicate ref's order here.
#pragma unroll
  for (int i = 0; i < NOUT; i++) {
    float v = acc[i];
    for (int off = 32; off > 0; off >>= 1) v += __shfl_down(v, off);
    if (lane == 0) mem2[(size_t)b * NOUT + i] += v;
  }
}

// ---------------------------------------------------------------------------
// Kernel 4: out = mem2 / num_steps
// ---------------------------------------------------------------------------
__global__ __launch_bounds__(256) void finalize_kernel(const float* __restrict__ mem2,
                                                       const int* __restrict__ ns,
                                                       float* __restrict__ out) {
  int i = blockIdx.x * blockDim.x + threadIdx.x;
  if (i < BSZ * NOUT) out[i] = mem2[i] / (float)(*ns);
}

// ---------------------------------------------------------------------------
extern "C" void kernel_launch(void* const* d_in, const int* in_sizes, int n_in,
                              void* d_out, int out_size, void* d_ws, size_t ws_size,
                              hipStream_t stream) {
  const float* inp = (const float*)d_in[0];
  const float* w1  = (const float*)d_in[1];
  const float* w2  = (const float*)d_in[2];
  const int*   dns = (const int*)d_in[3];
  float* out = (float*)d_out;

  char* ws = (char*)d_ws;
  size_t off = 0;
  uint8_t* enc = (uint8_t*)(ws + off);  off += (size_t)BSZ * KIN;          // 6.4 MB
  off = (off + 255) & ~(size_t)255;
  float* g    = (float*)(ws + off);     off += (size_t)BSZ * HID * 4;      // 26.2 MB
  float* mem1 = (float*)(ws + off);     off += (size_t)BSZ * HID * 4;      // 26.2 MB
  float* mem2 = (float*)(ws + off);     off += (size_t)BSZ * NOUT * 4;     // 0.33 MB

  (void)hipMemsetAsync(mem1, 0, (size_t)BSZ * HID * 4, stream);
  (void)hipMemsetAsync(mem2, 0, (size_t)BSZ * NOUT * 4, stream);

  // Step keys: partitionable split — key_t = threefry((0,42), (0,t)).
  uint32_t keys[NSTEP][2];
  for (int t = 0; t < NSTEP; t++)
    threefry2x32(0u, 42u, 0u, (uint32_t)t, &keys[t][0], &keys[t][1]);

  const int n_elem = BSZ * KIN;
  for (int t = 0; t < NSTEP; t++) {
    enc_kernel<<<(n_elem + 255) / 256, 256, 0, stream>>>(inp, enc, keys[t][0], keys[t][1]);
    gemm_kernel<<<dim3(BSZ / BM, HID / BN), 256, 0, stream>>>(enc, w1, g);
    update_kernel<<<BSZ / 4, 256, 0, stream>>>(g, mem1, w2, mem2);
  }
  finalize_kernel<<<(BSZ * NOUT + 255) / 256, 256, 0, stream>>>(mem2, dns, out);
}